// Round 11
// baseline (247.529 us; speedup 1.0000x reference)
//
#include <hip/hip_runtime.h>
#include <math.h>

#define PRE_NMS 2000
#define POST_NMS 1000
#define IOU_T 0.7f
#define IMGSZ 800.0f
#define NBINS 1024
#define NWORDS 32           // ceil(PRE_NMS/64)
#define NSLICE 16           // slices per image for hist/compact
#define SLOT 512            // cand capacity per slice (expected ~225)
#define CSTRIDE (NSLICE * SLOT)   // 8192 cand slots per image
#define SORTN 2048          // refined candidate cap (expected ~2003)
#define MROWS 2048          // padded row dim of transposed mask

typedef unsigned long long u64;

__device__ __forceinline__ unsigned key_of(float f) {
    unsigned u = __float_as_uint(f);
    return (u & 0x80000000u) ? ~u : (u | 0x80000000u);
}
__device__ __forceinline__ float inv_key(unsigned k) {
    unsigned u = (k & 0x80000000u) ? (k ^ 0x80000000u) : ~k;
    return __uint_as_float(u);
}

// ---- K1: per-slice 10-bit histogram (plain stores, no init, no atomics) ---
__global__ __launch_bounds__(256) void hist_kernel(
    const float* __restrict__ scores, int A, unsigned* __restrict__ ghist_s) {
  int b = blockIdx.x, slice = blockIdx.y;
  __shared__ unsigned h[NBINS];
  int tid = threadIdx.x;
  for (int i = tid; i < NBINS; i += 256) h[i] = 0;
  __syncthreads();
  int per = (A + NSLICE - 1) / NSLICE;
  int lo = slice * per, hi = min(lo + per, A);
  const float* sc = scores + (size_t)b * A;
  for (int i = lo + tid; i < hi; i += 256)
    atomicAdd(&h[key_of(sc[i]) >> 22], 1u);
  __syncthreads();
  unsigned* out = ghist_s + ((size_t)(b * NSLICE + slice) << 10);
  for (int i = tid; i < NBINS; i += 256) out[i] = h[i];
}

// ---- K2: T1 (in-block from summed slice hists) + per-slice compact + gh2 --
__global__ __launch_bounds__(256) void compact_kernel(
    const float* __restrict__ scores, int A, const unsigned* __restrict__ ghist_s,
    u64* __restrict__ cand, int* __restrict__ scnt,
    unsigned* __restrict__ gh2_s, int* __restrict__ above_s, int* __restrict__ T1w) {
  int b = blockIdx.x, slice = blockIdx.y;
  int tid = threadIdx.x;
  int lane = tid & 63, wave = tid >> 6;
  __shared__ unsigned sa[2][NBINS];
  __shared__ unsigned h2[NBINS];
  __shared__ int sT;
  // sum 16 slice hists (coalesced: consecutive bins per fixed slice)
  for (int i = tid; i < NBINS; i += 256) {
    unsigned s = 0;
    #pragma unroll 4
    for (int s16 = 0; s16 < NSLICE; ++s16)
      s += ghist_s[((size_t)(b * NSLICE + s16) << 10) + i];
    sa[0][i] = s;
    h2[i] = 0;
  }
  __syncthreads();
  int src = 0;
  for (int d = 1; d < NBINS; d <<= 1) {
    for (int i = tid; i < NBINS; i += 256)
      sa[src ^ 1][i] = sa[src][i] + ((i + d < NBINS) ? sa[src][i + d] : 0u);
    __syncthreads();
    src ^= 1;
  }
  for (int i = tid; i < NBINS; i += 256) {
    unsigned v = sa[src][i];
    unsigned nx = (i < NBINS - 1) ? sa[src][i + 1] : 0u;
    if (v >= PRE_NMS && nx < PRE_NMS) sT = i;
  }
  __syncthreads();
  int T = sT;
  if (slice == 0 && tid == 0) T1w[b] = T;
  // compact this slice: count, prefix, scatter into fixed segment
  int per = (A + NSLICE - 1) / NSLICE;
  int lo = slice * per, hi = min(lo + per, A);
  const float* sc = scores + (size_t)b * A;
  int cnt = 0, abv = 0;
  for (int i = lo + tid; i < hi; i += 256) {
    int bin = (int)(key_of(sc[i]) >> 22);
    cnt += (bin >= T);
    abv += (bin > T);
  }
  int pfx = cnt;
  #pragma unroll
  for (int d = 1; d < 64; d <<= 1) {
    int t2 = __shfl_up(pfx, d, 64);
    if (lane >= d) pfx += t2;
  }
  #pragma unroll
  for (int d = 32; d; d >>= 1) abv += __shfl_down(abv, d, 64);
  __shared__ int s_wt[4];
  __shared__ int s_ab[4];
  __shared__ int s_tot;
  if (lane == 63) s_wt[wave] = pfx;
  if (lane == 0) s_ab[wave] = abv;
  __syncthreads();
  if (tid == 0) {
    int acc = 0;
    #pragma unroll
    for (int w2 = 0; w2 < 4; ++w2) { int t3 = s_wt[w2]; s_wt[w2] = acc; acc += t3; }
    s_tot = acc;
    above_s[b * NSLICE + slice] = s_ab[0] + s_ab[1] + s_ab[2] + s_ab[3];
    scnt[b * NSLICE + slice] = min(acc, SLOT);
  }
  __syncthreads();
  int my_off = s_wt[wave] + (pfx - cnt);
  u64* cb = cand + (size_t)b * CSTRIDE + slice * SLOT;
  for (int i = lo + tid; i < hi; i += 256) {
    unsigned k = key_of(sc[i]);
    int bin = (int)(k >> 22);
    if (bin >= T) {
      if (my_off < SLOT) cb[my_off] = ((u64)k << 32) | (unsigned)(~i);
      my_off++;
      if (bin == T) atomicAdd(&h2[(k >> 12) & 1023], 1u);
    }
  }
  __syncthreads();
  unsigned* gh = gh2_s + ((size_t)(b * NSLICE + slice) << 10);
  for (int i = tid; i < NBINS; i += 256) gh[i] = h2[i];
}

// ---- K3: T2 + deterministic select + rank + decode (8 blocks/image) -------
__global__ __launch_bounds__(256) void rank_decode_kernel(
    const u64* __restrict__ cand, const int* __restrict__ scnt,
    const unsigned* __restrict__ gh2_s, const int* __restrict__ above_s,
    const int* __restrict__ T1w,
    const float* __restrict__ deltas, const float* __restrict__ anchors, int A,
    float* __restrict__ boxes, float* __restrict__ topk_logit) {
  int b = blockIdx.x, ci = blockIdx.y;
  int tid = threadIdx.x;
  int lane = tid & 63, wave = tid >> 6;
  __shared__ unsigned sa[2][NBINS];       // 8 KiB
  __shared__ u64 keys[SORTN];             // 16 KiB
  __shared__ int s_T2, s_tot;
  __shared__ int s_wt[4];
  __shared__ int p[NSLICE + 1];
  __shared__ int sc_l[NSLICE];
  // sum gh2 slices + suffix scan -> T2
  for (int i = tid; i < NBINS; i += 256) {
    unsigned s = 0;
    #pragma unroll 4
    for (int s16 = 0; s16 < NSLICE; ++s16)
      s += gh2_s[((size_t)(b * NSLICE + s16) << 10) + i];
    sa[0][i] = s;
  }
  if (tid == 0) {
    int acc = 0;
    #pragma unroll
    for (int s16 = 0; s16 < NSLICE; ++s16) {
      int c = scnt[b * NSLICE + s16];
      sc_l[s16] = c;
      p[s16] = acc;
      acc += c;
    }
    p[NSLICE] = acc;
  }
  __syncthreads();
  int src = 0;
  for (int d = 1; d < NBINS; d <<= 1) {
    for (int i = tid; i < NBINS; i += 256)
      sa[src ^ 1][i] = sa[src][i] + ((i + d < NBINS) ? sa[src][i + d] : 0u);
    __syncthreads();
    src ^= 1;
  }
  int above = 0;
  #pragma unroll
  for (int s16 = 0; s16 < NSLICE; ++s16) above += above_s[b * NSLICE + s16];
  for (int i = tid; i < NBINS; i += 256) {
    unsigned v = sa[src][i];
    unsigned nx = (i < NBINS - 1) ? sa[src][i + 1] : 0u;
    if (above + (int)v >= PRE_NMS && above + (int)nx < PRE_NMS) s_T2 = i;
  }
  __syncthreads();
  unsigned th20 = ((unsigned)T1w[b] << 10) | (unsigned)s_T2;
  const u64* cb = cand + (size_t)b * CSTRIDE;
  int n = p[NSLICE];
  int chunk = (n + 255) / 256;
  int st = min(tid * chunk, n), en = min(st + chunk, n);
  // pass 1: count passing keys in [st,en) (segment-ordered walk)
  int cnt = 0;
  {
    int sl = 0;
    while (sl < NSLICE && p[sl + 1] <= st) sl++;
    int idx = st - p[sl];
    for (int g = st; g < en; ++g) {
      while (idx >= sc_l[sl]) { sl++; idx = 0; }
      u64 cv = cb[sl * SLOT + idx];
      cnt += ((unsigned)(cv >> 44) >= th20);
      idx++;
    }
  }
  int pfx = cnt;
  #pragma unroll
  for (int d = 1; d < 64; d <<= 1) {
    int t2 = __shfl_up(pfx, d, 64);
    if (lane >= d) pfx += t2;
  }
  if (lane == 63) s_wt[wave] = pfx;
  __syncthreads();
  if (tid == 0) {
    int acc = 0;
    #pragma unroll
    for (int w2 = 0; w2 < 4; ++w2) { int t3 = s_wt[w2]; s_wt[w2] = acc; acc += t3; }
    s_tot = acc;
  }
  __syncthreads();
  int pos = s_wt[wave] + (pfx - cnt);
  // pass 2: scatter into LDS (identical order in all 8 blocks of this image)
  {
    int sl = 0;
    while (sl < NSLICE && p[sl + 1] <= st) sl++;
    int idx = st - p[sl];
    for (int g = st; g < en; ++g) {
      while (idx >= sc_l[sl]) { sl++; idx = 0; }
      u64 cv = cb[sl * SLOT + idx];
      if ((unsigned)(cv >> 44) >= th20) {
        if (pos < SORTN) keys[pos] = cv;
        pos++;
      }
      idx++;
    }
  }
  int nsel = min(s_tot, SORTN);
  for (int i = tid; i < SORTN; i += 256)
    if (i >= nsel) keys[i] = 0ULL;
  __syncthreads();
  // rank slice ci (256 keys), decode
  int i0 = ci * 256 + tid;
  u64 my = keys[i0];
  int rank = 0;
  const ulonglong2* k2 = (const ulonglong2*)keys;
  #pragma unroll 4
  for (int j = 0; j < SORTN / 2; ++j) {
    ulonglong2 kk = k2[j];                 // uniform addr -> LDS broadcast
    rank += (kk.x > my) + (kk.y > my);
  }
  if (i0 < nsel && rank < PRE_NMS) {
    int a = (int)(~(unsigned)my);
    topk_logit[b * PRE_NMS + rank] = inv_key((unsigned)(my >> 32));
    const float CLIP = 4.135166556742356f;  // log(1000/16)
    float4 dl = ((const float4*)deltas)[(size_t)b * A + a];
    float4 an = ((const float4*)anchors)[a];
    float wa = __fsub_rn(an.z, an.x);
    float ha = __fsub_rn(an.w, an.y);
    float cxa = __fadd_rn(an.x, __fmul_rn(0.5f, wa));
    float cya = __fadd_rn(an.y, __fmul_rn(0.5f, ha));
    float dw = fminf(dl.z, CLIP), dh = fminf(dl.w, CLIP);
    float cx = __fadd_rn(__fmul_rn(dl.x, wa), cxa);
    float cy = __fadd_rn(__fmul_rn(dl.y, ha), cya);
    float w2 = __fmul_rn((float)exp((double)dw), wa);
    float h2f = __fmul_rn((float)exp((double)dh), ha);
    float x1 = __fsub_rn(cx, __fmul_rn(0.5f, w2));
    float y1 = __fsub_rn(cy, __fmul_rn(0.5f, h2f));
    float x2 = __fadd_rn(cx, __fmul_rn(0.5f, w2));
    float y2 = __fadd_rn(cy, __fmul_rn(0.5f, h2f));
    x1 = fminf(fmaxf(x1, 0.f), IMGSZ);
    y1 = fminf(fmaxf(y1, 0.f), IMGSZ);
    x2 = fminf(fmaxf(x2, 0.f), IMGSZ);
    y2 = fminf(fmaxf(y2, 0.f), IMGSZ);
    ((float4*)boxes)[(size_t)b * PRE_NMS + rank] = make_float4(x1, y1, x2, y2);
  }
}

// ---- K4: IoU tiles, one wave per 64x64 upper-triangle tile ----------------
__global__ __launch_bounds__(64) void iou_tile(
    const float* __restrict__ boxes, u64* __restrict__ maskT) {
  int k = blockIdx.x;       // 0..527 -> (ti <= wj) pair
  int b = blockIdx.y;
  int wj = (int)((sqrtf(8.0f * k + 1.0f) - 1.0f) * 0.5f);
  while ((wj + 1) * (wj + 2) / 2 <= k) ++wj;
  while (wj * (wj + 1) / 2 > k) --wj;
  int ti = k - wj * (wj + 1) / 2;
  int lane = threadIdx.x;
  int i = ti * 64 + lane;
  const float4* bb = (const float4*)boxes + (size_t)b * PRE_NMS;
  __shared__ float4 sbox[64];
  int jg = wj * 64 + lane;
  sbox[lane] = bb[min(jg, PRE_NMS - 1)];
  float4 A4 = bb[min(i, PRE_NMS - 1)];
  __syncthreads();
  float area_a = __fmul_rn(__fsub_rn(A4.z, A4.x), __fsub_rn(A4.w, A4.y));
  u64 m = 0;
  #pragma unroll 8
  for (int jj = 0; jj < 64; ++jj) {
    float4 Bb = sbox[jj];                  // uniform address -> broadcast
    float area_b = __fmul_rn(__fsub_rn(Bb.z, Bb.x), __fsub_rn(Bb.w, Bb.y));
    float ltx = fmaxf(A4.x, Bb.x), lty = fmaxf(A4.y, Bb.y);
    float rbx = fminf(A4.z, Bb.z), rby = fminf(A4.w, Bb.w);
    float iw = fmaxf(__fsub_rn(rbx, ltx), 0.f);
    float ih = fmaxf(__fsub_rn(rby, lty), 0.f);
    float inter = __fmul_rn(iw, ih);
    float denom = __fadd_rn(__fsub_rn(__fadd_rn(area_a, area_b), inter), 1e-9f);
    float iou = inter / denom;
    int j = wj * 64 + jj;
    if (j > i && iou > IOU_T) m |= 1ULL << jj;
  }
  maskT[((size_t)b * NWORDS + wj) * MROWS + i] = m;   // coalesced
}

// ---- K5: NMS scan v7 — pipelined: phase2(c-1) overlaps phase1(c) ----------
#define WSTRIDE 65
__global__ __launch_bounds__(256, 1) void nms_scan(
    const u64* __restrict__ maskT, const float* __restrict__ boxes,
    const float* __restrict__ logits, float* __restrict__ out) {
  int b = blockIdx.x;
  int tid = threadIdx.x;
  int wave = tid >> 6, lane = tid & 63;
  __shared__ u64 buf[3][NWORDS * WSTRIDE];   // 3 x 16.25 KiB
  __shared__ u64 s_keep[NWORDS];
  __shared__ u64 s_cur[2];
  if (tid < NWORDS) s_keep[tid] = (tid == NWORDS - 1) ? 0xFFFFULL : ~0ULL;
  const u64* mb = maskT + (size_t)b * NWORDS * MROWS;
  int w = tid >> 3;          // word 0..31
  int sub = tid & 7;         // rows sub*8 .. sub*8+7 of the chunk
  uint4 nx0, nx1, nx2, nx3;
  { // load + store chunk 0
    const uint4* src = (const uint4*)(mb + (size_t)w * MROWS + sub * 8);
    uint4 a0 = src[0], a1 = src[1], a2 = src[2], a3 = src[3];
    u64* dst = &buf[0][w * WSTRIDE + sub * 8];
    dst[0] = ((u64)a0.y << 32) | a0.x;  dst[1] = ((u64)a0.w << 32) | a0.z;
    dst[2] = ((u64)a1.y << 32) | a1.x;  dst[3] = ((u64)a1.w << 32) | a1.z;
    dst[4] = ((u64)a2.y << 32) | a2.x;  dst[5] = ((u64)a2.w << 32) | a2.z;
    dst[6] = ((u64)a3.y << 32) | a3.x;  dst[7] = ((u64)a3.w << 32) | a3.z;
  }
  if (w >= 1) { // prefetch chunk 1 (upper-triangle words only)
    const uint4* src = (const uint4*)(mb + (size_t)w * MROWS + 64 + sub * 8);
    nx0 = src[0]; nx1 = src[1]; nx2 = src[2]; nx3 = src[3];
  }
  __syncthreads();
  for (int c = 0; c < NWORDS; ++c) {
    if (c + 1 < NWORDS && w >= c + 1) {
      u64* dst = &buf[(c + 1) % 3][w * WSTRIDE + sub * 8];
      dst[0] = ((u64)nx0.y << 32) | nx0.x;  dst[1] = ((u64)nx0.w << 32) | nx0.z;
      dst[2] = ((u64)nx1.y << 32) | nx1.x;  dst[3] = ((u64)nx1.w << 32) | nx1.z;
      dst[4] = ((u64)nx2.y << 32) | nx2.x;  dst[5] = ((u64)nx2.w << 32) | nx2.z;
      dst[6] = ((u64)nx3.y << 32) | nx3.x;  dst[7] = ((u64)nx3.w << 32) | nx3.z;
    }
    if (c + 2 < NWORDS && w >= c + 2) {
      const uint4* src = (const uint4*)(mb + (size_t)w * MROWS + (c + 2) * 64 + sub * 8);
      nx0 = src[0]; nx1 = src[1]; nx2 = src[2]; nx3 = src[3];
    }
    if (wave == 0) {
      u64 diag = buf[c % 3][c * WSTRIDE + lane];
      unsigned dlo = (unsigned)diag, dhi = (unsigned)(diag >> 32);
      u64 k0 = s_keep[c];
      unsigned clo = __builtin_amdgcn_readfirstlane((unsigned)k0);
      unsigned chi = __builtin_amdgcn_readfirstlane((unsigned)(k0 >> 32));
      #pragma unroll
      for (int bb = 0; bb < 32; ++bb) {
        unsigned rlo = __builtin_amdgcn_readlane(dlo, bb);
        unsigned rhi = __builtin_amdgcn_readlane(dhi, bb);
        unsigned msk = 0u - ((clo >> bb) & 1u);
        clo &= ~(rlo & msk);
        chi &= ~(rhi & msk);
      }
      #pragma unroll
      for (int bb = 0; bb < 32; ++bb) {
        unsigned rlo = __builtin_amdgcn_readlane(dlo, bb + 32);
        unsigned rhi = __builtin_amdgcn_readlane(dhi, bb + 32);
        unsigned msk = 0u - ((chi >> bb) & 1u);
        clo &= ~(rlo & msk);
        chi &= ~(rhi & msk);
      }
      u64 cur = ((u64)chi << 32) | clo;
      if (lane == 0) { s_keep[c] = cur; s_cur[c & 1] = cur; }
      if (c + 1 < NWORDS) {
        u64 row = buf[c % 3][(c + 1) * WSTRIDE + lane];
        u64 bit = (cur >> lane) & 1ULL;
        u64 v = row & (0ULL - bit);
        v |= __shfl_xor(v, 1, 64);
        v |= __shfl_xor(v, 2, 64);
        v |= __shfl_xor(v, 4, 64);
        v |= __shfl_xor(v, 8, 64);
        v |= __shfl_xor(v, 16, 64);
        v |= __shfl_xor(v, 32, 64);
        if (lane == 0 && v) atomicAnd(&s_keep[c + 1], ~v);
      }
    } else if (c >= 1) {
      u64 kept = s_cur[(c - 1) & 1];
      int g = lane >> 3, s = lane & 7;
      const u64* bbuf = &buf[(c - 1) % 3][0];
      for (int idx = (wave - 1) + 3 * g; idx < NWORDS - 1 - c; idx += 24) {
        int w2 = c + 1 + idx;
        u64 v = 0;
        #pragma unroll
        for (int k = 0; k < 8; ++k) {
          int r = s + 8 * k;
          u64 bit = (kept >> r) & 1ULL;
          v |= bbuf[w2 * WSTRIDE + r] & (0ULL - bit);
        }
        v |= __shfl_xor(v, 1, 64);
        v |= __shfl_xor(v, 2, 64);
        v |= __shfl_xor(v, 4, 64);
        if (s == 0 && v) atomicAnd(&s_keep[w2], ~v);
      }
    }
    __syncthreads();
  }
  // fused emit: rank kept boxes, write [box, sigmoid]; zero rows >= total
  __shared__ int pre[NWORDS];
  __shared__ int s_tot2;
  if (tid == 0) {
    int acc = 0;
    for (int ww = 0; ww < NWORDS; ++ww) {
      pre[ww] = acc;
      acc += __popcll(s_keep[ww]);
    }
    s_tot2 = acc;
  }
  __syncthreads();
  const float* lg_b = logits + b * PRE_NMS;
  const float4* bx_b = (const float4*)boxes + (size_t)b * PRE_NMS;
  for (int i = tid; i < PRE_NMS; i += 256) {
    u64 wv = s_keep[i >> 6];
    if ((wv >> (i & 63)) & 1) {
      int rank = pre[i >> 6] + __popcll(wv & ((1ULL << (i & 63)) - 1ULL));
      if (rank < POST_NMS) {
        float4 bx = bx_b[i];
        float lg = lg_b[i];
        float e = (float)exp(-(double)lg);
        float pp = 1.0f / (1.0f + e);
        float* o = out + ((size_t)b * POST_NMS + rank) * 5;
        o[0] = bx.x; o[1] = bx.y; o[2] = bx.z; o[3] = bx.w; o[4] = pp;
      }
    }
  }
  int tot = s_tot2;
  for (int j = tid; j < POST_NMS; j += 256) {
    if (j >= tot) {
      float* o = out + ((size_t)b * POST_NMS + j) * 5;
      o[0] = 0.f; o[1] = 0.f; o[2] = 0.f; o[3] = 0.f; o[4] = 0.f;
    }
  }
}

extern "C" void kernel_launch(void* const* d_in, const int* in_sizes, int n_in,
                              void* d_out, int out_size, void* d_ws, size_t ws_size,
                              hipStream_t stream) {
  const float* scores  = (const float*)d_in[0];
  const float* deltas  = (const float*)d_in[1];
  const float* anchors = (const float*)d_in[2];
  int A = in_sizes[2] / 4;          // 159882
  int B = in_sizes[0] / A;          // 16

  char* ws = (char*)d_ws;
  size_t off = 0;
  auto alloc = [&](size_t bytes) {
    void* p = ws + off;
    off += (bytes + 255) & ~(size_t)255;
    return p;
  };
  unsigned* ghist_s = (unsigned*)alloc((size_t)B * NSLICE * NBINS * 4);  // 1 MiB
  unsigned* gh2_s   = (unsigned*)alloc((size_t)B * NSLICE * NBINS * 4);  // 1 MiB
  int*      scnt    = (int*)alloc((size_t)B * NSLICE * 4);
  int*      above_s = (int*)alloc((size_t)B * NSLICE * 4);
  int*      T1w     = (int*)alloc((size_t)B * 4);
  u64*      cand    = (u64*)alloc((size_t)B * CSTRIDE * 8);              // 1 MiB
  float*    topk_lg = (float*)alloc((size_t)B * PRE_NMS * 4);
  float*    boxes   = (float*)alloc((size_t)B * PRE_NMS * 16);
  u64*      maskT   = (u64*)alloc((size_t)B * NWORDS * MROWS * 8);

  // no memsets needed: every workspace word consumed is written first by a
  // prior kernel (per-slice plain stores), and nms_scan fully writes d_out.
  hist_kernel<<<dim3(B, NSLICE), 256, 0, stream>>>(scores, A, ghist_s);
  compact_kernel<<<dim3(B, NSLICE), 256, 0, stream>>>(
      scores, A, ghist_s, cand, scnt, gh2_s, above_s, T1w);
  rank_decode_kernel<<<dim3(B, SORTN / 256), 256, 0, stream>>>(
      cand, scnt, gh2_s, above_s, T1w, deltas, anchors, A, boxes, topk_lg);
  int ntiles = NWORDS * (NWORDS + 1) / 2;   // 528 upper-triangle tiles
  iou_tile<<<dim3(ntiles, B), 64, 0, stream>>>(boxes, maskT);
  nms_scan<<<B, 256, 0, stream>>>(maskT, boxes, topk_lg, (float*)d_out);
}